// Round 2
// baseline (139.725 us; speedup 1.0000x reference)
//
#include <hip/hip_runtime.h>

// Problem constants: m=4, h=16, t=1024, d=128, MAX_REL=128.
constexpr int D_DIM = 128;
constexpr int T_Q   = 1024;
constexpr int NPE   = 257;               // 2*MAX_REL + 1 pe rows
constexpr int WAVES = 8;                 // 512-thread block
constexpr int RPW   = 8;                 // rows per wave per iteration
constexpr int BLOCK_THREADS  = WAVES * 64;
constexpr int ROWS_PER_BLOCK = 256;      // 65536 rows / 256 blocks

// LDS: pe (rotated) 131.6 KB + per-wave rel scratch 8 KB = 139.8 KB (<160 KB, 1 block/CU)
__global__ __launch_bounds__(BLOCK_THREADS, 2)
void rpe_fused(const float* __restrict__ Q,
               const float* __restrict__ pe,
               float* __restrict__ out)
{
    // pe row j element d stored at pe_lds[j*128 + ((d + 4*j) & 127)].
    // Lane l owns j in {l, l+64, l+128, l+192}; 4*j mod 128 == 4*l mod 128 for all
    // four, so one physical column po=(d0+4l)&127 serves all 4 ds_read_b128.
    // Banks: start word (d0+4l)%32 -> lanes 0..7 tile all 32 banks (conflict-free).
    // Window never wraps: po is a multiple of 4 and <= 124.
    __shared__ float pe_lds[NPE * 128];
    __shared__ float scratch[WAVES][256];

    const int tid = threadIdx.x;
    const int w   = tid >> 6;
    const int l   = tid & 63;

    // ---- stage pe into LDS with rotation (once per block) ----
    for (int flat = tid; flat < NPE * 128; flat += BLOCK_THREADS) {
        const int r = flat >> 7;
        const int d = flat & 127;
        pe_lds[r * 128 + ((d + 4 * r) & 127)] = pe[flat];
    }
    __syncthreads();

    const int rowBase = blockIdx.x * ROWS_PER_BLOCK;

    for (int it = 0; it < ROWS_PER_BLOCK / (WAVES * RPW); ++it) {
        const int gRow0 = rowBase + it * (WAVES * RPW) + w * RPW;
        // wave-uniform row base -> q loads become scalar (s_load), feeding FMA
        // via SGPR operand: zero DS/VALU cost for q in the inner loop.
        const int uRow0 = __builtin_amdgcn_readfirstlane(gRow0);
        const float* __restrict__ Qw = Q + (size_t)uRow0 * D_DIM;

        float acc[RPW][4];
        #pragma unroll
        for (int r = 0; r < RPW; ++r)
            #pragma unroll
            for (int k = 0; k < 4; ++k) acc[r][k] = 0.f;

        // ---- main loop: acc[r][k] = dot(q_row_r, pe_row_(l+64k)) ----
        #pragma unroll 2
        for (int d0 = 0; d0 < D_DIM; d0 += 4) {
            const int po = (d0 + 4 * l) & 127;
            const float4 p0 = *reinterpret_cast<const float4*>(&pe_lds[(l      ) * 128 + po]);
            const float4 p1 = *reinterpret_cast<const float4*>(&pe_lds[(l +  64) * 128 + po]);
            const float4 p2 = *reinterpret_cast<const float4*>(&pe_lds[(l + 128) * 128 + po]);
            const float4 p3 = *reinterpret_cast<const float4*>(&pe_lds[(l + 192) * 128 + po]);
            #pragma unroll
            for (int r = 0; r < RPW; ++r) {
                const float4 q = *reinterpret_cast<const float4*>(Qw + r * D_DIM + d0);
                acc[r][0] = fmaf(q.x, p0.x, fmaf(q.y, p0.y, fmaf(q.z, p0.z, fmaf(q.w, p0.w, acc[r][0]))));
                acc[r][1] = fmaf(q.x, p1.x, fmaf(q.y, p1.y, fmaf(q.z, p1.z, fmaf(q.w, p1.w, acc[r][1]))));
                acc[r][2] = fmaf(q.x, p2.x, fmaf(q.y, p2.y, fmaf(q.z, p2.z, fmaf(q.w, p2.w, acc[r][2]))));
                acc[r][3] = fmaf(q.x, p3.x, fmaf(q.y, p3.y, fmaf(q.z, p3.z, fmaf(q.w, p3.w, acc[r][3]))));
            }
        }

        // ---- rel[256] per row: lanes split d, 6-step butterfly reduce ----
        float rel256[RPW];
        {
            // row 256 rotation: (4*256)&127 == 0 -> unrotated
            const float pa = pe_lds[256 * 128 + l];
            const float pb = pe_lds[256 * 128 + l + 64];
            #pragma unroll
            for (int r = 0; r < RPW; ++r) {
                float part = Qw[r * D_DIM + l] * pa + Qw[r * D_DIM + l + 64] * pb;
                #pragma unroll
                for (int off = 32; off; off >>= 1)
                    part += __shfl_xor(part, off, 64);
                rel256[r] = part;
            }
        }

        // ---- epilogue: spill window, region-split gather, coalesced stores ----
        #pragma unroll 1
        for (int r = 0; r < RPW; ++r) {
            scratch[w][l      ] = acc[r][0];
            scratch[w][l +  64] = acc[r][1];
            scratch[w][l + 128] = acc[r][2];
            scratch[w][l + 192] = acc[r][3];
            asm volatile("s_waitcnt lgkmcnt(0)" ::: "memory");

            const int gRow = gRow0 + r;
            const int t = gRow & (T_Q - 1);
            float* orow = out + (size_t)gRow * T_Q;
            const float r256 = rel256[r];
            const float r0   = __builtin_amdgcn_readfirstlane(acc[r][0]); // rel[j=0]

            #pragma unroll
            for (int k = 0; k < 4; ++k) {
                const int s0 = 4 * l + 256 * k;
                const int j0 = t + 128 - s0;          // jraw at c=0 (max of the group)
                float4 v;
                if (j0 <= 0) {                         // whole group right-clipped -> rel[0]
                    v = make_float4(r0, r0, r0, r0);
                } else if (j0 >= 259) {                // whole group left-clipped -> rel[256]
                    v = make_float4(r256, r256, r256, r256);
                } else {                               // middle: reversed window gather
                    float x[4];
                    #pragma unroll
                    for (int c = 0; c < 4; ++c) {
                        const int jr = j0 - c;
                        const int jc = jr < 0 ? 0 : (jr > 255 ? 255 : jr);
                        const float sv = scratch[w][jc];
                        x[c] = (jr >= 256) ? r256 : ((jr <= 0) ? r0 : sv);
                    }
                    v = make_float4(x[0], x[1], x[2], x[3]);
                }
                reinterpret_cast<float4*>(orow)[l + 64 * k] = v;
            }
            // DS pipe is in-order per wave: next r's scratch writes cannot pass
            // this r's gather reads. scratch is per-wave -> no cross-wave hazard.
        }
    }
}

extern "C" void kernel_launch(void* const* d_in, const int* in_sizes, int n_in,
                              void* d_out, int out_size, void* d_ws, size_t ws_size,
                              hipStream_t stream)
{
    const float* Q  = (const float*)d_in[0];
    // d_in[1] is K: only its shape matters (t_k = 1024), data unused.
    const float* pe = (const float*)d_in[2];
    float* out = (float*)d_out;

    const int total_rows = in_sizes[0] / D_DIM;        // m*h*t = 65536
    const int grid = total_rows / ROWS_PER_BLOCK;      // 256 -> one block per CU
    rpe_fused<<<grid, BLOCK_THREADS, 0, stream>>>(Q, pe, out);
}